// Round 1
// baseline (642.056 us; speedup 1.0000x reference)
//
#include <hip/hip_runtime.h>

// InnerProductDecoder2: fused edge gather + gumbel-argmax + sigmoid select.
// Decision path computed in fp64 to match a float64 numpy reference bitwise
// on the discrete argmax (boundary margin ~3e-6; fp32 reordering error ~1e-6
// would flip edges).

constexpr int D = 64;

// Detect whether edge_index was passed as int64 or int32.
// int32 data read as int64 combines two random indices -> >= 2^32 almost surely.
__global__ void detect_i64_kernel(const void* __restrict__ eidx, long long nmax,
                                  int nsamp, int* __restrict__ flag)
{
    if (blockIdx.x == 0 && threadIdx.x == 0) {
        const long long* p = (const long long*)eidx;
        int ok = 1;
        for (int i = 0; i < nsamp; ++i) {
            long long v = p[i];
            if (v < 0 || v >= nmax) { ok = 0; break; }
        }
        *flag = ok;
    }
}

__global__ __launch_bounds__(256) void ipd2_fused_kernel(
    const float* __restrict__ z1,
    const float* __restrict__ gu,
    const int* __restrict__ temp_p,
    const void* __restrict__ eidx,
    float* __restrict__ out,
    int E,
    const int* __restrict__ i64flag)
{
    const bool is64 = (*i64flag != 0);
    const bool tpos = (*temp_p > 0);   // sign of temp decides argmax direction

    const int sub = threadIdx.x & 15;                    // lane within 16-lane group
    int gid = (int)((blockIdx.x * (long long)blockDim.x + threadIdx.x) >> 4);
    const int ngroups = (int)(((long long)gridDim.x * blockDim.x) >> 4);

    for (int e = gid; e < E; e += ngroups) {
        long long s, d;
        if (is64) {
            const long long* p = (const long long*)eidx;
            s = p[e];
            d = p[(long long)E + e];
        } else {
            const int* p = (const int*)eidx;
            s = p[e];
            d = p[(long long)E + e];
        }

        // Each of 16 lanes loads one float4 of each row (coalesced 256B/row).
        const float4 a = *(const float4*)(z1 + s * D + sub * 4);
        const float4 b = *(const float4*)(z1 + d * D + sub * 4);

        double local;
        if (sub == 0) {
            // columns 0,1 are excluded from the dot product (z1[:,2:])
            local = (double)a.z * (double)b.z + (double)a.w * (double)b.w;
        } else {
            local = (double)a.x * (double)b.x + (double)a.y * (double)b.y
                  + (double)a.z * (double)b.z + (double)a.w * (double)b.w;
        }

        // butterfly reduce across the 16-lane group (f64, order-insensitive at 1e-14)
        #pragma unroll
        for (int m = 1; m < 16; m <<= 1)
            local += __shfl_xor(local, m, 64);

        if (sub == 0) {
            const double vf = local;                       // value_feature (== vf_sg)
            const double vn = (double)a.x + (double)b.x;   // value_network

            const float2 uu = *(const float2*)(gu + 2ll * e);
            double w0 = fmin(fmax((double)uu.x, 1e-10), 1.0 - 1e-10);
            double w1 = fmin(fmax((double)uu.y, 1e-10), 1.0 - 1e-10);
            double g0 = -log(-log(w0));
            double g1 = -log(-log(w1));

            // argmax(softmax((la+g)/t)): monotone in (la+g) for t>0, reversed t<0;
            // tie -> index 0 -> flag = 1.
            const double n0 = vf + g0;
            const double n1 = g1;
            const bool flag = tpos ? (n0 >= n1) : (n0 <= n1);

            const double x  = flag ? vf : vn;
            const double sg = 1.0 / (1.0 + exp(-x));

            out[e] = (float)sg;                       // output 0: out
            out[(long long)E + e] = flag ? 1.0f : 0.0f; // output 1: a[:,0]
        }
    }
}

extern "C" void kernel_launch(void* const* d_in, const int* in_sizes, int n_in,
                              void* d_out, int out_size, void* d_ws, size_t ws_size,
                              hipStream_t stream)
{
    const float* z1     = (const float*)d_in[0];
    const float* gu     = (const float*)d_in[1];
    const int*   temp_p = (const int*)d_in[2];
    const void*  eidx   = d_in[3];
    float*       out    = (float*)d_out;

    const int E = in_sizes[1] / 2;          // gumbel_u is (E,2)
    const long long N = in_sizes[0] / D;    // z1 is (N,64)

    int* i64flag = (int*)d_ws;
    detect_i64_kernel<<<1, 64, 0, stream>>>(eidx, N, 128, i64flag);

    const int blocks = 4096;
    ipd2_fused_kernel<<<blocks, 256, 0, stream>>>(z1, gu, temp_p, eidx, out, E, i64flag);
}

// Round 2
// 339.100 us; speedup vs baseline: 1.8934x; 1.8934x over previous
//
#include <hip/hip_runtime.h>

// InnerProductDecoder2: fused edge gather + gumbel-argmax + sigmoid select.
// f32 fast path for everything; edges whose argmax margin is within TAU of
// zero are recomputed inline in f64 (mirroring a float64 numpy reference) so
// the discrete flag never flips vs. the reference. Expected borderline edges
// at TAU=4e-3: ~1300 of 3.2M (f32 path error bound ~2e-5 -> 200x safety).

constexpr int D = 64;
#define TAU 0.004f

// Detect whether edge_index was passed as int64 or int32.
// int32 data read as int64 combines two random indices -> out of range almost surely.
__global__ void detect_i64_kernel(const void* __restrict__ eidx, long long nmax,
                                  int nsamp, int* __restrict__ flag)
{
    if (blockIdx.x == 0 && threadIdx.x == 0) {
        const long long* p = (const long long*)eidx;
        int ok = 1;
        for (int i = 0; i < nsamp; ++i) {
            long long v = p[i];
            if (v < 0 || v >= nmax) { ok = 0; break; }
        }
        *flag = ok;
    }
}

__global__ __launch_bounds__(256) void ipd2_kernel(
    const float* __restrict__ z1,
    const float* __restrict__ gu,
    const int* __restrict__ temp_p,
    const void* __restrict__ eidx,
    float* __restrict__ out,
    int E,
    const int* __restrict__ i64flag)
{
    const bool is64 = (*i64flag != 0);
    const bool tpos = (*temp_p > 0);   // sign of temp decides argmax direction

    // per-wave private LDS strips (wave-synchronous: written and read by the
    // same 64-lane wave; DS ops are in-order per wave, compiler inserts lgkmcnt)
    __shared__ float s_vf[4][64];
    __shared__ float s_vn[4][64];

    const int lane = threadIdx.x & 63;
    const int wid  = threadIdx.x >> 6;       // wave within block (0..3)
    const int grp  = lane >> 4;              // 16-lane group (0..3)
    const int sub  = lane & 15;

    const long long wgid   = ((long long)blockIdx.x * blockDim.x + threadIdx.x) >> 6;
    const long long nwaves = ((long long)gridDim.x * blockDim.x) >> 6;

    const int*       p32 = (const int*)eidx;
    const long long* p64 = (const long long*)eidx;

    for (long long base = wgid * 64; base < E; base += nwaves * 64) {
        // ---- phase 1: dot products. group g handles edges base+g*16+it ----
        for (int it = 0; it < 16; ++it) {
            const long long e = base + grp * 16 + it;
            if (e < E) {
                long long s, d;
                if (is64) { s = p64[e]; d = p64[E + e]; }
                else      { s = p32[e]; d = p32[E + e]; }
                // 16 lanes each load one float4 of each row (coalesced 256B/row)
                const float4 a = *(const float4*)(z1 + s * D + sub * 4);
                const float4 b = *(const float4*)(z1 + d * D + sub * 4);
                // columns 0,1 excluded from the dot (z1[:,2:])
                float loc = a.z * b.z + a.w * b.w;
                if (sub != 0) loc += a.x * b.x + a.y * b.y;
                #pragma unroll
                for (int m = 1; m < 16; m <<= 1)
                    loc += __shfl_xor(loc, m, 64);     // stays within 16-lane group
                if (sub == 0) {
                    s_vf[wid][grp * 16 + it] = loc;
                    s_vn[wid][grp * 16 + it] = a.x + b.x;
                }
            }
        }

        // ---- phase 2: tails, all 64 lanes active, lane j -> edge base+j ----
        const long long e = base + lane;
        if (e < E) {
            const float vf = s_vf[wid][lane];
            const float vn = s_vn[wid][lane];
            const float2 uu = *(const float2*)(gu + 2 * e);

            // upper clip 1-1e-10 rounds to 1.0f and all inputs are < 1, so it
            // is a no-op for both f32 and f64 semantics; clamp defensively.
            const float u0 = fminf(fmaxf(uu.x, 1e-10f), 0.99999994f);
            const float u1 = fminf(fmaxf(uu.y, 1e-10f), 0.99999994f);
            const float g0 = -logf(-logf(u0));
            const float g1 = -logf(-logf(u1));

            const float n0 = vf + g0;
            // argmax(softmax((la+g)/t)) is monotone in la+g for t>0, reversed
            // for t<0; tie -> index 0 -> flag = 1.
            bool  flag  = tpos ? (n0 >= g1) : (n0 <= g1);
            float x     = flag ? vf : vn;
            float sg    = 1.0f / (1.0f + expf(-x));
            float oflag = flag ? 1.0f : 0.0f;

            if (fabsf(n0 - g1) < TAU) {
                // borderline: exact f64 recompute mirroring the np reference
                long long s, d;
                if (is64) { s = p64[e]; d = p64[E + e]; }
                else      { s = p32[e]; d = p32[E + e]; }
                const float* ra = z1 + s * D;
                const float* rb = z1 + d * D;
                double acc = 0.0;
                for (int j = 2; j < D; ++j)
                    acc += (double)ra[j] * (double)rb[j];
                const double w0 = fmin(fmax((double)uu.x, 1e-10), 1.0 - 1e-10);
                const double w1 = fmin(fmax((double)uu.y, 1e-10), 1.0 - 1e-10);
                const double G0 = -log(-log(w0));
                const double G1 = -log(-log(w1));
                const double N0 = acc + G0;
                const bool f2 = tpos ? (N0 >= G1) : (N0 <= G1);
                const double xx = f2 ? acc : ((double)ra[0] + (double)rb[0]);
                sg    = (float)(1.0 / (1.0 + exp(-xx)));
                oflag = f2 ? 1.0f : 0.0f;
            }

            out[e]     = sg;     // output 0: out
            out[E + e] = oflag;  // output 1: a[:,0]
        }
    }
}

extern "C" void kernel_launch(void* const* d_in, const int* in_sizes, int n_in,
                              void* d_out, int out_size, void* d_ws, size_t ws_size,
                              hipStream_t stream)
{
    const float* z1     = (const float*)d_in[0];
    const float* gu     = (const float*)d_in[1];
    const int*   temp_p = (const int*)d_in[2];
    const void*  eidx   = d_in[3];
    float*       out    = (float*)d_out;

    const int E = in_sizes[1] / 2;          // gumbel_u is (E,2)
    const long long N = in_sizes[0] / D;    // z1 is (N,64)

    int* i64flag = (int*)d_ws;
    detect_i64_kernel<<<1, 64, 0, stream>>>(eidx, N, 128, i64flag);

    const int blocks = 2048;
    ipd2_kernel<<<blocks, 256, 0, stream>>>(z1, gu, temp_p, eidx, out, E, i64flag);
}

// Round 3
// 223.891 us; speedup vs baseline: 2.8677x; 1.5146x over previous
//
#include <hip/hip_runtime.h>

// InnerProductDecoder2: fused edge gather + gumbel-argmax + sigmoid select.
// f32 fast path; borderline argmax edges (|margin|<TAU) recomputed in f64
// mirroring the float64 numpy reference so the discrete flag never flips.
// Round-3 restructure: batch index hoist + reg broadcast, x4-unrolled gather
// phase (8 loads in flight/wave), gumbel VALU chain hoisted over gather
// latency. Attacks the latency-bound profile (VALUBusy 19%, HBM 26%).

constexpr int D = 64;
#define TAU 0.004f

// Detect whether edge_index was passed as int64 or int32.
__global__ void detect_i64_kernel(const void* __restrict__ eidx, long long nmax,
                                  int nsamp, int* __restrict__ flag)
{
    if (blockIdx.x == 0 && threadIdx.x == 0) {
        const long long* p = (const long long*)eidx;
        int ok = 1;
        for (int i = 0; i < nsamp; ++i) {
            long long v = p[i];
            if (v < 0 || v >= nmax) { ok = 0; break; }
        }
        *flag = ok;
    }
}

__global__ __launch_bounds__(256, 4) void ipd2_kernel(
    const float* __restrict__ z1,
    const float* __restrict__ gu,
    const int* __restrict__ temp_p,
    const void* __restrict__ eidx,
    float* __restrict__ out,
    int E,
    const int* __restrict__ i64flag)
{
    const bool is64 = (*i64flag != 0);
    const bool tpos = (*temp_p > 0);   // sign of temp decides argmax direction

    // per-wave private LDS strips (wave-synchronous, no barriers)
    __shared__ float s_vf[4][64];
    __shared__ float s_vn[4][64];

    const int lane = threadIdx.x & 63;
    const int wid  = threadIdx.x >> 6;
    const int grp  = lane >> 4;              // 16-lane group (0..3)
    const int sub  = lane & 15;

    const long long wgid   = ((long long)blockIdx.x * blockDim.x + threadIdx.x) >> 6;
    const long long nwaves = ((long long)gridDim.x * blockDim.x) >> 6;

    const int*       p32 = (const int*)eidx;
    const long long* p64 = (const long long*)eidx;

    for (long long base = wgid * 64; base < E; base += nwaves * 64) {
        const long long eL  = base + lane;
        const bool      okL = eL < E;

        // ---- batch prefetch: indices (fit int32: values < N) + gumbel ----
        int sj = 0, dj = 0;
        float2 uu = make_float2(0.5f, 0.5f);
        if (okL) {
            if (is64) { sj = (int)p64[eL]; dj = (int)p64[E + eL]; }
            else      { sj = p32[eL];      dj = p32[E + eL]; }
            uu = *(const float2*)(gu + 2 * eL);
        }
        // tail VALU hoisted ahead of the gather phase (overlaps latency)
        const float u0 = fminf(fmaxf(uu.x, 1e-10f), 0.99999994f);
        const float u1 = fminf(fmaxf(uu.y, 1e-10f), 0.99999994f);
        const float g0 = -logf(-logf(u0));
        const float g1 = -logf(-logf(u1));

        // ---- phase 1: dots; group g -> edges base+g*16+it ----
        if (base + 64 <= E) {
            #pragma unroll
            for (int it0 = 0; it0 < 16; it0 += 4) {
                float4 a[4], b[4];
                #pragma unroll
                for (int k = 0; k < 4; ++k) {
                    const int sl = grp * 16 + it0 + k;   // lane holding this edge's idx
                    const int s  = __shfl(sj, sl, 64);
                    const int d  = __shfl(dj, sl, 64);
                    a[k] = *(const float4*)(z1 + (size_t)s * D + sub * 4);
                    b[k] = *(const float4*)(z1 + (size_t)d * D + sub * 4);
                }
                #pragma unroll
                for (int k = 0; k < 4; ++k) {
                    float loc = a[k].z * b[k].z + a[k].w * b[k].w;
                    if (sub != 0) loc += a[k].x * b[k].x + a[k].y * b[k].y;
                    #pragma unroll
                    for (int m = 1; m < 16; m <<= 1)
                        loc += __shfl_xor(loc, m, 64);
                    if (sub == 0) {
                        s_vf[wid][grp * 16 + it0 + k] = loc;
                        s_vn[wid][grp * 16 + it0 + k] = a[k].x + b[k].x;
                    }
                }
            }
        } else {
            // generic tail batch (not hit when 64 | E)
            for (int it = 0; it < 16; ++it) {
                const long long e = base + grp * 16 + it;
                if (e < E) {
                    const int s = __shfl(sj, grp * 16 + it, 64);
                    const int d = __shfl(dj, grp * 16 + it, 64);
                    const float4 a = *(const float4*)(z1 + (size_t)s * D + sub * 4);
                    const float4 b = *(const float4*)(z1 + (size_t)d * D + sub * 4);
                    float loc = a.z * b.z + a.w * b.w;
                    if (sub != 0) loc += a.x * b.x + a.y * b.y;
                    #pragma unroll
                    for (int m = 1; m < 16; m <<= 1)
                        loc += __shfl_xor(loc, m, 64);
                    if (sub == 0) {
                        s_vf[wid][grp * 16 + it] = loc;
                        s_vn[wid][grp * 16 + it] = a.x + b.x;
                    }
                }
            }
        }

        // ---- phase 2: tails, all 64 lanes active, lane j -> edge base+j ----
        if (okL) {
            const float vf = s_vf[wid][lane];
            const float vn = s_vn[wid][lane];

            const float n0 = vf + g0;
            // argmax(softmax((la+g)/t)) monotone in la+g for t>0, reversed t<0;
            // tie -> index 0 -> flag = 1.
            bool  flag  = tpos ? (n0 >= g1) : (n0 <= g1);
            float x     = flag ? vf : vn;
            float sg    = 1.0f / (1.0f + expf(-x));
            float oflag = flag ? 1.0f : 0.0f;

            if (fabsf(n0 - g1) < TAU) {
                // borderline: exact f64 recompute mirroring the np reference
                long long s, d;
                if (is64) { s = p64[eL]; d = p64[E + eL]; }
                else      { s = p32[eL]; d = p32[E + eL]; }
                const float* ra = z1 + s * D;
                const float* rb = z1 + d * D;
                double acc = 0.0;
                for (int j = 2; j < D; ++j)
                    acc += (double)ra[j] * (double)rb[j];
                const double w0 = fmin(fmax((double)uu.x, 1e-10), 1.0 - 1e-10);
                const double w1 = fmin(fmax((double)uu.y, 1e-10), 1.0 - 1e-10);
                const double G0 = -log(-log(w0));
                const double G1 = -log(-log(w1));
                const double N0 = acc + G0;
                const bool f2 = tpos ? (N0 >= G1) : (N0 <= G1);
                const double xx = f2 ? acc : ((double)ra[0] + (double)rb[0]);
                sg    = (float)(1.0 / (1.0 + exp(-xx)));
                oflag = f2 ? 1.0f : 0.0f;
            }

            out[eL]     = sg;     // output 0: out
            out[E + eL] = oflag;  // output 1: a[:,0]
        }
    }
}

extern "C" void kernel_launch(void* const* d_in, const int* in_sizes, int n_in,
                              void* d_out, int out_size, void* d_ws, size_t ws_size,
                              hipStream_t stream)
{
    const float* z1     = (const float*)d_in[0];
    const float* gu     = (const float*)d_in[1];
    const int*   temp_p = (const int*)d_in[2];
    const void*  eidx   = d_in[3];
    float*       out    = (float*)d_out;

    const int E = in_sizes[1] / 2;          // gumbel_u is (E,2)
    const long long N = in_sizes[0] / D;    // z1 is (N,64)

    int* i64flag = (int*)d_ws;
    detect_i64_kernel<<<1, 64, 0, stream>>>(eidx, N, 128, i64flag);

    const int blocks = 2048;
    ipd2_kernel<<<blocks, 256, 0, stream>>>(z1, gu, temp_p, eidx, out, E, i64flag);
}

// Round 4
// 215.441 us; speedup vs baseline: 2.9802x; 1.0392x over previous
//
#include <hip/hip_runtime.h>

// InnerProductDecoder2: fused edge gather + gumbel-argmax + sigmoid select.
// f32 fast path; borderline argmax edges (|margin|<TAU) recomputed in f64
// mirroring the float64 numpy reference so the discrete flag never flips.
// Round-4: x8 gather unroll (16 float4 loads in flight/wave) + cross-batch
// prefetch of indices/gumbel (kills the per-batch index-load stall).
// Attacks the latency-bound profile (HBM 41%, VALUBusy 15%, ~8KB/CU in flight).

constexpr int D = 64;
#define TAU 0.004f

// Detect whether edge_index was passed as int64 or int32.
__global__ void detect_i64_kernel(const void* __restrict__ eidx, long long nmax,
                                  int nsamp, int* __restrict__ flag)
{
    if (blockIdx.x == 0 && threadIdx.x == 0) {
        const long long* p = (const long long*)eidx;
        int ok = 1;
        for (int i = 0; i < nsamp; ++i) {
            long long v = p[i];
            if (v < 0 || v >= nmax) { ok = 0; break; }
        }
        *flag = ok;
    }
}

__global__ __launch_bounds__(256, 4) void ipd2_kernel(
    const float* __restrict__ z1,
    const float* __restrict__ gu,
    const int* __restrict__ temp_p,
    const void* __restrict__ eidx,
    float* __restrict__ out,
    int E,
    const int* __restrict__ i64flag)
{
    const bool is64 = (*i64flag != 0);
    const bool tpos = (*temp_p > 0);   // sign of temp decides argmax direction

    // per-wave private LDS strips (wave-synchronous, no barriers)
    __shared__ float s_vf[4][64];
    __shared__ float s_vn[4][64];

    const int lane = threadIdx.x & 63;
    const int wid  = threadIdx.x >> 6;
    const int grp  = lane >> 4;              // 16-lane group (0..3)
    const int sub  = lane & 15;

    const long long wgid   = ((long long)blockIdx.x * blockDim.x + threadIdx.x) >> 6;
    const long long nwaves = ((long long)gridDim.x * blockDim.x) >> 6;
    const long long bstep  = nwaves * 64;

    const int*       p32 = (const int*)eidx;
    const long long* p64 = (const long long*)eidx;

    const long long base0 = wgid * 64;
    if (base0 >= E) return;

    // ---- prologue: load batch-0 indices + gumbel ----
    long long e0 = base0 + lane; if (e0 >= E) e0 = E - 1;
    int sj, dj;
    if (is64) { sj = (int)p64[e0]; dj = (int)p64[E + e0]; }
    else      { sj = p32[e0];      dj = p32[E + e0]; }
    float2 uu = *(const float2*)(gu + 2 * e0);

    for (long long base = base0; base < E; base += bstep) {
        const long long eL  = base + lane;
        const bool      okL = eL < E;

        // ---- prefetch NEXT batch's indices + gumbel (branchless, clamped) ----
        long long eN = base + bstep + lane;
        if (eN >= E) eN = E - 1;               // harmless clamped load
        int nsj, ndj;
        if (is64) { nsj = (int)p64[eN]; ndj = (int)p64[E + eN]; }
        else      { nsj = p32[eN];      ndj = p32[E + eN]; }
        const float2 nuu = *(const float2*)(gu + 2 * eN);

        // tail VALU hoisted ahead of the gather phase (overlaps latency)
        const float u0 = fminf(fmaxf(uu.x, 1e-10f), 0.99999994f);
        const float u1 = fminf(fmaxf(uu.y, 1e-10f), 0.99999994f);
        const float g0 = -logf(-logf(u0));
        const float g1 = -logf(-logf(u1));

        // ---- phase 1: dots; group g -> edges base+g*16+it ----
        if (base + 64 <= E) {
            #pragma unroll
            for (int it0 = 0; it0 < 16; it0 += 8) {
                float4 a[8], b[8];
                #pragma unroll
                for (int k = 0; k < 8; ++k) {
                    const int sl = grp * 16 + it0 + k;   // lane holding this edge's idx
                    const int s  = __shfl(sj, sl, 64);
                    const int d  = __shfl(dj, sl, 64);
                    a[k] = *(const float4*)(z1 + (size_t)s * D + sub * 4);
                    b[k] = *(const float4*)(z1 + (size_t)d * D + sub * 4);
                }
                #pragma unroll
                for (int k = 0; k < 8; ++k) {
                    float loc = a[k].z * b[k].z + a[k].w * b[k].w;
                    if (sub != 0) loc += a[k].x * b[k].x + a[k].y * b[k].y;
                    #pragma unroll
                    for (int m = 1; m < 16; m <<= 1)
                        loc += __shfl_xor(loc, m, 64);
                    if (sub == 0) {
                        s_vf[wid][grp * 16 + it0 + k] = loc;
                        s_vn[wid][grp * 16 + it0 + k] = a[k].x + b[k].x;
                    }
                }
            }
        } else {
            // generic tail batch (not hit when 64 | E)
            for (int it = 0; it < 16; ++it) {
                const long long e = base + grp * 16 + it;
                if (e < E) {
                    const int s = __shfl(sj, grp * 16 + it, 64);
                    const int d = __shfl(dj, grp * 16 + it, 64);
                    const float4 a = *(const float4*)(z1 + (size_t)s * D + sub * 4);
                    const float4 b = *(const float4*)(z1 + (size_t)d * D + sub * 4);
                    float loc = a.z * b.z + a.w * b.w;
                    if (sub != 0) loc += a.x * b.x + a.y * b.y;
                    #pragma unroll
                    for (int m = 1; m < 16; m <<= 1)
                        loc += __shfl_xor(loc, m, 64);
                    if (sub == 0) {
                        s_vf[wid][grp * 16 + it] = loc;
                        s_vn[wid][grp * 16 + it] = a.x + b.x;
                    }
                }
            }
        }

        // ---- phase 2: tails, all 64 lanes active, lane j -> edge base+j ----
        if (okL) {
            const float vf = s_vf[wid][lane];
            const float vn = s_vn[wid][lane];

            const float n0 = vf + g0;
            // argmax(softmax((la+g)/t)) monotone in la+g for t>0, reversed t<0;
            // tie -> index 0 -> flag = 1.
            bool  flag  = tpos ? (n0 >= g1) : (n0 <= g1);
            float x     = flag ? vf : vn;
            float sg    = 1.0f / (1.0f + expf(-x));
            float oflag = flag ? 1.0f : 0.0f;

            if (fabsf(n0 - g1) < TAU) {
                // borderline: exact f64 recompute mirroring the np reference
                long long s, d;
                if (is64) { s = p64[eL]; d = p64[E + eL]; }
                else      { s = p32[eL]; d = p32[E + eL]; }
                const float* ra = z1 + s * D;
                const float* rb = z1 + d * D;
                double acc = 0.0;
                for (int j = 2; j < D; ++j)
                    acc += (double)ra[j] * (double)rb[j];
                const double w0 = fmin(fmax((double)uu.x, 1e-10), 1.0 - 1e-10);
                const double w1 = fmin(fmax((double)uu.y, 1e-10), 1.0 - 1e-10);
                const double G0 = -log(-log(w0));
                const double G1 = -log(-log(w1));
                const double N0 = acc + G0;
                const bool f2 = tpos ? (N0 >= G1) : (N0 <= G1);
                const double xx = f2 ? acc : ((double)ra[0] + (double)rb[0]);
                sg    = (float)(1.0 / (1.0 + exp(-xx)));
                oflag = f2 ? 1.0f : 0.0f;
            }

            out[eL]     = sg;     // output 0: out
            out[E + eL] = oflag;  // output 1: a[:,0]
        }

        // rotate prefetched batch state
        sj = nsj; dj = ndj; uu = nuu;
    }
}

extern "C" void kernel_launch(void* const* d_in, const int* in_sizes, int n_in,
                              void* d_out, int out_size, void* d_ws, size_t ws_size,
                              hipStream_t stream)
{
    const float* z1     = (const float*)d_in[0];
    const float* gu     = (const float*)d_in[1];
    const int*   temp_p = (const int*)d_in[2];
    const void*  eidx   = d_in[3];
    float*       out    = (float*)d_out;

    const int E = in_sizes[1] / 2;          // gumbel_u is (E,2)
    const long long N = in_sizes[0] / D;    // z1 is (N,64)

    int* i64flag = (int*)d_ws;
    detect_i64_kernel<<<1, 64, 0, stream>>>(eidx, N, 128, i64flag);

    const int blocks = 4096;
    ipd2_kernel<<<blocks, 256, 0, stream>>>(z1, gu, temp_p, eidx, out, E, i64flag);
}

// Round 5
// 158.483 us; speedup vs baseline: 4.0513x; 1.3594x over previous
//
#include <hip/hip_runtime.h>
#include <hip/hip_fp16.h>

// InnerProductDecoder2: fused edge gather + gumbel-argmax + sigmoid select.
// Round-5: gather from an fp16 copy of z1 (12.8 MB, 128 B/row = 1 cache line)
// to halve the L2-miss traffic that plateaued at ~3.4 TB/s. Decision margin
// |vf+g0-g1| < TAU (=0.05, ~16 sigma of the fp16 dot error) falls back to an
// exact f64 recompute from the original f32 z1, mirroring the float64 numpy
// reference, so the discrete flag never flips. Sigmoid-arg error <= ~1.6e-2
// -> output error <= 4e-3 (threshold 2e-2).

constexpr int D = 64;
#define TAU 0.05f

// Detect whether edge_index was passed as int64 or int32.
__global__ void detect_i64_kernel(const void* __restrict__ eidx, long long nmax,
                                  int nsamp, int* __restrict__ flag)
{
    if (blockIdx.x == 0 && threadIdx.x == 0) {
        const long long* p = (const long long*)eidx;
        int ok = 1;
        for (int i = 0; i < nsamp; ++i) {
            long long v = p[i];
            if (v < 0 || v >= nmax) { ok = 0; break; }
        }
        *flag = ok;
    }
}

// f32 -> f16 conversion of z1 (4 elems per thread, fully coalesced)
__global__ __launch_bounds__(256) void cvt_half_kernel(
    const float* __restrict__ z1, __half* __restrict__ zh, long long n4)
{
    long long i = (long long)blockIdx.x * blockDim.x + threadIdx.x;
    const long long stride = (long long)gridDim.x * blockDim.x;
    for (; i < n4; i += stride) {
        const float4 v = *(const float4*)(z1 + i * 4);
        __half2 h0 = __floats2half2_rn(v.x, v.y);
        __half2 h1 = __floats2half2_rn(v.z, v.w);
        uint2 o;
        o.x = __builtin_bit_cast(unsigned int, h0);
        o.y = __builtin_bit_cast(unsigned int, h1);
        *(uint2*)(zh + i * 4) = o;
    }
}

static __device__ __forceinline__ float2 h2f2(unsigned int u)
{
    return __half22float2(__builtin_bit_cast(__half2, u));
}

// ---------------- fp16-gather main kernel ----------------
__global__ __launch_bounds__(256, 4) void ipd2_h_kernel(
    const float* __restrict__ z1,        // original f32 (borderline fallback)
    const __half* __restrict__ zh,       // fp16 copy (fast path)
    const float* __restrict__ gu,
    const int* __restrict__ temp_p,
    const void* __restrict__ eidx,
    float* __restrict__ out,
    int E,
    const int* __restrict__ i64flag)
{
    const bool is64 = (*i64flag != 0);
    const bool tpos = (*temp_p > 0);

    __shared__ float s_vf[4][64];
    __shared__ float s_vn[4][64];

    const int lane = threadIdx.x & 63;
    const int wid  = threadIdx.x >> 6;
    const int grp  = lane >> 4;              // 16-lane group (0..3)
    const int sub  = lane & 15;

    const long long wgid   = ((long long)blockIdx.x * blockDim.x + threadIdx.x) >> 6;
    const long long nwaves = ((long long)gridDim.x * blockDim.x) >> 6;
    const long long bstep  = nwaves * 64;

    const int*       p32 = (const int*)eidx;
    const long long* p64 = (const long long*)eidx;

    const long long base0 = wgid * 64;
    if (base0 >= E) return;

    // prologue: batch-0 indices + gumbel
    long long e0 = base0 + lane; if (e0 >= E) e0 = E - 1;
    int sj, dj;
    if (is64) { sj = (int)p64[e0]; dj = (int)p64[E + e0]; }
    else      { sj = p32[e0];      dj = p32[E + e0]; }
    float2 uu = *(const float2*)(gu + 2 * e0);

    for (long long base = base0; base < E; base += bstep) {
        const long long eL  = base + lane;
        const bool      okL = eL < E;

        // prefetch NEXT batch's indices + gumbel (branchless, clamped)
        long long eN = base + bstep + lane;
        if (eN >= E) eN = E - 1;
        int nsj, ndj;
        if (is64) { nsj = (int)p64[eN]; ndj = (int)p64[E + eN]; }
        else      { nsj = p32[eN];      ndj = p32[E + eN]; }
        const float2 nuu = *(const float2*)(gu + 2 * eN);

        // tail VALU hoisted over gather latency
        const float u0 = fminf(fmaxf(uu.x, 1e-10f), 0.99999994f);
        const float u1 = fminf(fmaxf(uu.y, 1e-10f), 0.99999994f);
        const float g0 = -logf(-logf(u0));
        const float g1 = -logf(-logf(u1));

        // ---- phase 1: dots; group g -> edges base+g*16+k; lane covers elems [4sub,4sub+4)
        if (base + 64 <= E) {
            uint2 a[16], b[16];
            #pragma unroll
            for (int k = 0; k < 16; ++k) {
                const int sl = grp * 16 + k;
                const int s  = __shfl(sj, sl, 64);
                const int d  = __shfl(dj, sl, 64);
                a[k] = *(const uint2*)(zh + (size_t)s * D + sub * 4);
                b[k] = *(const uint2*)(zh + (size_t)d * D + sub * 4);
            }
            #pragma unroll
            for (int k = 0; k < 16; ++k) {
                const float2 fa0 = h2f2(a[k].x), fa1 = h2f2(a[k].y);
                const float2 fb0 = h2f2(b[k].x), fb1 = h2f2(b[k].y);
                float loc = fa1.x * fb1.x + fa1.y * fb1.y;   // elems 2,3 of lane
                if (sub != 0) loc += fa0.x * fb0.x + fa0.y * fb0.y;  // elems 0,1
                #pragma unroll
                for (int m = 1; m < 16; m <<= 1)
                    loc += __shfl_xor(loc, m, 64);
                if (sub == 0) {
                    s_vf[wid][grp * 16 + k] = loc;
                    s_vn[wid][grp * 16 + k] = fa0.x + fb0.x;  // elem 0 of each row
                }
            }
        } else {
            for (int it = 0; it < 16; ++it) {
                const long long e = base + grp * 16 + it;
                if (e < E) {
                    const int s = __shfl(sj, grp * 16 + it, 64);
                    const int d = __shfl(dj, grp * 16 + it, 64);
                    const uint2 a = *(const uint2*)(zh + (size_t)s * D + sub * 4);
                    const uint2 b = *(const uint2*)(zh + (size_t)d * D + sub * 4);
                    const float2 fa0 = h2f2(a.x), fa1 = h2f2(a.y);
                    const float2 fb0 = h2f2(b.x), fb1 = h2f2(b.y);
                    float loc = fa1.x * fb1.x + fa1.y * fb1.y;
                    if (sub != 0) loc += fa0.x * fb0.x + fa0.y * fb0.y;
                    #pragma unroll
                    for (int m = 1; m < 16; m <<= 1)
                        loc += __shfl_xor(loc, m, 64);
                    if (sub == 0) {
                        s_vf[wid][grp * 16 + it] = loc;
                        s_vn[wid][grp * 16 + it] = fa0.x + fb0.x;
                    }
                }
            }
        }

        // ---- phase 2: tails, lane j -> edge base+j ----
        if (okL) {
            const float vf = s_vf[wid][lane];
            const float vn = s_vn[wid][lane];

            const float n0 = vf + g0;
            bool  flag  = tpos ? (n0 >= g1) : (n0 <= g1);
            float x     = flag ? vf : vn;
            float sg    = 1.0f / (1.0f + expf(-x));
            float oflag = flag ? 1.0f : 0.0f;

            if (fabsf(n0 - g1) < TAU) {
                // borderline: exact f64 recompute from f32 z1 (matches np ref)
                long long s, d;
                if (is64) { s = p64[eL]; d = p64[E + eL]; }
                else      { s = p32[eL]; d = p32[E + eL]; }
                const float* ra = z1 + s * D;
                const float* rb = z1 + d * D;
                double acc = 0.0;
                for (int j = 2; j < D; ++j)
                    acc += (double)ra[j] * (double)rb[j];
                const double w0 = fmin(fmax((double)uu.x, 1e-10), 1.0 - 1e-10);
                const double w1 = fmin(fmax((double)uu.y, 1e-10), 1.0 - 1e-10);
                const double G0 = -log(-log(w0));
                const double G1 = -log(-log(w1));
                const double N0 = acc + G0;
                const bool f2 = tpos ? (N0 >= G1) : (N0 <= G1);
                const double xx = f2 ? acc : ((double)ra[0] + (double)rb[0]);
                sg    = (float)(1.0 / (1.0 + exp(-xx)));
                oflag = f2 ? 1.0f : 0.0f;
            }

            out[eL]     = sg;
            out[E + eL] = oflag;
        }

        sj = nsj; dj = ndj; uu = nuu;
    }
}

// ---------------- f32 fallback (round-4 kernel) for small ws_size ----------------
__global__ __launch_bounds__(256, 4) void ipd2_f32_kernel(
    const float* __restrict__ z1,
    const float* __restrict__ gu,
    const int* __restrict__ temp_p,
    const void* __restrict__ eidx,
    float* __restrict__ out,
    int E,
    const int* __restrict__ i64flag)
{
    const bool is64 = (*i64flag != 0);
    const bool tpos = (*temp_p > 0);

    __shared__ float s_vf[4][64];
    __shared__ float s_vn[4][64];

    const int lane = threadIdx.x & 63;
    const int wid  = threadIdx.x >> 6;
    const int grp  = lane >> 4;
    const int sub  = lane & 15;

    const long long wgid   = ((long long)blockIdx.x * blockDim.x + threadIdx.x) >> 6;
    const long long nwaves = ((long long)gridDim.x * blockDim.x) >> 6;
    const long long bstep  = nwaves * 64;

    const int*       p32 = (const int*)eidx;
    const long long* p64 = (const long long*)eidx;

    const long long base0 = wgid * 64;
    if (base0 >= E) return;

    long long e0 = base0 + lane; if (e0 >= E) e0 = E - 1;
    int sj, dj;
    if (is64) { sj = (int)p64[e0]; dj = (int)p64[E + e0]; }
    else      { sj = p32[e0];      dj = p32[E + e0]; }
    float2 uu = *(const float2*)(gu + 2 * e0);

    for (long long base = base0; base < E; base += bstep) {
        const long long eL  = base + lane;
        const bool      okL = eL < E;

        long long eN = base + bstep + lane;
        if (eN >= E) eN = E - 1;
        int nsj, ndj;
        if (is64) { nsj = (int)p64[eN]; ndj = (int)p64[E + eN]; }
        else      { nsj = p32[eN];      ndj = p32[E + eN]; }
        const float2 nuu = *(const float2*)(gu + 2 * eN);

        const float u0 = fminf(fmaxf(uu.x, 1e-10f), 0.99999994f);
        const float u1 = fminf(fmaxf(uu.y, 1e-10f), 0.99999994f);
        const float g0 = -logf(-logf(u0));
        const float g1 = -logf(-logf(u1));

        if (base + 64 <= E) {
            #pragma unroll
            for (int it0 = 0; it0 < 16; it0 += 8) {
                float4 a[8], b[8];
                #pragma unroll
                for (int k = 0; k < 8; ++k) {
                    const int sl = grp * 16 + it0 + k;
                    const int s  = __shfl(sj, sl, 64);
                    const int d  = __shfl(dj, sl, 64);
                    a[k] = *(const float4*)(z1 + (size_t)s * D + sub * 4);
                    b[k] = *(const float4*)(z1 + (size_t)d * D + sub * 4);
                }
                #pragma unroll
                for (int k = 0; k < 8; ++k) {
                    float loc = a[k].z * b[k].z + a[k].w * b[k].w;
                    if (sub != 0) loc += a[k].x * b[k].x + a[k].y * b[k].y;
                    #pragma unroll
                    for (int m = 1; m < 16; m <<= 1)
                        loc += __shfl_xor(loc, m, 64);
                    if (sub == 0) {
                        s_vf[wid][grp * 16 + it0 + k] = loc;
                        s_vn[wid][grp * 16 + it0 + k] = a[k].x + b[k].x;
                    }
                }
            }
        } else {
            for (int it = 0; it < 16; ++it) {
                const long long e = base + grp * 16 + it;
                if (e < E) {
                    const int s = __shfl(sj, grp * 16 + it, 64);
                    const int d = __shfl(dj, grp * 16 + it, 64);
                    const float4 a = *(const float4*)(z1 + (size_t)s * D + sub * 4);
                    const float4 b = *(const float4*)(z1 + (size_t)d * D + sub * 4);
                    float loc = a.z * b.z + a.w * b.w;
                    if (sub != 0) loc += a.x * b.x + a.y * b.y;
                    #pragma unroll
                    for (int m = 1; m < 16; m <<= 1)
                        loc += __shfl_xor(loc, m, 64);
                    if (sub == 0) {
                        s_vf[wid][grp * 16 + it] = loc;
                        s_vn[wid][grp * 16 + it] = a.x + b.x;
                    }
                }
            }
        }

        if (okL) {
            const float vf = s_vf[wid][lane];
            const float vn = s_vn[wid][lane];
            const float n0 = vf + g0;
            bool  flag  = tpos ? (n0 >= g1) : (n0 <= g1);
            float x     = flag ? vf : vn;
            float sg    = 1.0f / (1.0f + expf(-x));
            float oflag = flag ? 1.0f : 0.0f;

            if (fabsf(n0 - g1) < 0.004f) {
                long long s, d;
                if (is64) { s = p64[eL]; d = p64[E + eL]; }
                else      { s = p32[eL]; d = p32[E + eL]; }
                const float* ra = z1 + s * D;
                const float* rb = z1 + d * D;
                double acc = 0.0;
                for (int j = 2; j < D; ++j)
                    acc += (double)ra[j] * (double)rb[j];
                const double w0 = fmin(fmax((double)uu.x, 1e-10), 1.0 - 1e-10);
                const double w1 = fmin(fmax((double)uu.y, 1e-10), 1.0 - 1e-10);
                const double G0 = -log(-log(w0));
                const double G1 = -log(-log(w1));
                const double N0 = acc + G0;
                const bool f2 = tpos ? (N0 >= G1) : (N0 <= G1);
                const double xx = f2 ? acc : ((double)ra[0] + (double)rb[0]);
                sg    = (float)(1.0 / (1.0 + exp(-xx)));
                oflag = f2 ? 1.0f : 0.0f;
            }

            out[eL]     = sg;
            out[E + eL] = oflag;
        }

        sj = nsj; dj = ndj; uu = nuu;
    }
}

extern "C" void kernel_launch(void* const* d_in, const int* in_sizes, int n_in,
                              void* d_out, int out_size, void* d_ws, size_t ws_size,
                              hipStream_t stream)
{
    const float* z1     = (const float*)d_in[0];
    const float* gu     = (const float*)d_in[1];
    const int*   temp_p = (const int*)d_in[2];
    const void*  eidx   = d_in[3];
    float*       out    = (float*)d_out;

    const int E = in_sizes[1] / 2;          // gumbel_u is (E,2)
    const long long N = in_sizes[0] / D;    // z1 is (N,64)

    int* i64flag = (int*)d_ws;
    detect_i64_kernel<<<1, 64, 0, stream>>>(eidx, N, 128, i64flag);

    const size_t need = 4096 + (size_t)N * D * sizeof(__half);
    if (ws_size >= need) {
        __half* zh = (__half*)((char*)d_ws + 4096);
        cvt_half_kernel<<<2048, 256, 0, stream>>>(z1, zh, (long long)N * D / 4);
        ipd2_h_kernel<<<4096, 256, 0, stream>>>(z1, zh, gu, temp_p, eidx, out, E, i64flag);
    } else {
        ipd2_f32_kernel<<<4096, 256, 0, stream>>>(z1, gu, temp_p, eidx, out, E, i64flag);
    }
}